// Round 8
// baseline (893.853 us; speedup 1.0000x reference)
//
#include <hip/hip_runtime.h>

#define NPTS 4096
#define CH 64
#define BATCH 8
#define KNN 20
#define KSEL 32
#define NEG_SLOPE 0.2f
#define EPSV 1e-5f
#define NEG_INF (-3.4e38f)

typedef short s8v __attribute__((ext_vector_type(8)));    // 8 bf16 (4 VGPRs)
typedef float f16v __attribute__((ext_vector_type(16)));  // MFMA acc

// ---------------- K0: xx[b,n] = sum_c x[b,c,n]^2 (exact fp32) --------------
__global__ void k_xx(const float* __restrict__ x, float* __restrict__ xx) {
  int t = blockIdx.x * 256 + threadIdx.x;
  int b = t >> 12, n = t & (NPTS - 1);
  const float* xp = x + ((size_t)b * CH * NPTS) + n;
  float s = 0.f;
#pragma unroll
  for (int c = 0; c < CH; ++c) { float v = xp[(size_t)c * NPTS]; s = fmaf(v, v, s); }
  xx[t] = s;
}

// ---------------- K_cvt: x[b,c,n] fp32 -> xt_hi/xt_lo [b,n,c] bf16 ----------
__global__ void k_cvt(const float* __restrict__ x, ushort* __restrict__ xh,
                      ushort* __restrict__ xl) {
  __shared__ float T[64 * 68];
  int tid = threadIdx.x;
  int nb = blockIdx.x, b = blockIdx.y, n0 = nb * 64;
  const float* xb = x + (size_t)b * CH * NPTS;
#pragma unroll
  for (int k = 0; k < 4; ++k) {
    int q = tid + 256 * k;                     // 0..1023
    int c = q >> 4, n4 = (q & 15) << 2;
    float4 v = *(const float4*)(xb + (size_t)c * NPTS + n0 + n4);
    *(float4*)(T + c * 68 + n4) = v;
  }
  __syncthreads();
  size_t obase = (size_t)b * NPTS * 64;
#pragma unroll
  for (int k = 0; k < 2; ++k) {
    int z = tid + 256 * k;                     // 0..511
    int n = z >> 3, c8 = (z & 7) << 3;
    ushort h[8], l[8];
#pragma unroll
    for (int j = 0; j < 8; ++j) {
      float v = T[(c8 + j) * 68 + n];
      unsigned u = __float_as_uint(v);
      unsigned hb = (u + 0x7FFFu + ((u >> 16) & 1u)) >> 16;   // RNE bf16
      float hf = __uint_as_float(hb << 16);
      float lv = v - hf;                                       // exact (Sterbenz)
      unsigned u2 = __float_as_uint(lv);
      unsigned lb = (u2 + 0x7FFFu + ((u2 >> 16) & 1u)) >> 16;
      h[j] = (ushort)hb; l[j] = (ushort)lb;
    }
    *(int4*)(xh + obase + (size_t)(n0 + n) * 64 + c8) = *(int4*)h;
    *(int4*)(xl + obase + (size_t)(n0 + n) * 64 + c8) = *(int4*)l;
  }
}

// ---------------- K2: P'[t,o], Q'[t,o] ----------------
__global__ void k_pq(const float* __restrict__ x, const float* __restrict__ W,
                     const float* __restrict__ gamma, const float* __restrict__ beta,
                     const float* __restrict__ rmean, const float* __restrict__ rvar,
                     float* __restrict__ P, float* __restrict__ Q) {
  __shared__ float Ws1[CH * CH];
  __shared__ float Wsd[CH * CH];
  int tid = threadIdx.x;
  for (int i = tid; i < CH * CH; i += 256) {
    int o = i & 63, c = i >> 6;
    float s = gamma[o] * rsqrtf(rvar[o] + EPSV);
    float w1 = W[o * 128 + c], w2 = W[o * 128 + 64 + c];
    Ws1[c * 64 + o] = w1 * s;
    Wsd[c * 64 + o] = (w2 - w1) * s;
  }
  __syncthreads();
  int o = tid & 63, ng = tid >> 6;
  float s = gamma[o] * rsqrtf(rvar[o] + EPSV);
  float shift = beta[o] - rmean[o] * s;
  int base = blockIdx.x * 16;
  for (int rp = 0; rp < 4; ++rp) {
    int t = base + rp * 4 + ng;
    int b = t >> 12, n = t & (NPTS - 1);
    const float* xp = x + ((size_t)b * CH * NPTS) + n;
    float accp = 0.f, accq = 0.f;
#pragma unroll 8
    for (int c = 0; c < CH; ++c) {
      float xv = xp[(size_t)c * NPTS];
      accp = fmaf(xv, Ws1[c * 64 + o], accp);
      accq = fmaf(xv, Wsd[c * 64 + o], accq);
    }
    P[(size_t)t * 64 + o] = accp;
    Q[(size_t)t * 64 + o] = accq + shift;
  }
}

// ---------------- K1: MFMA split-bf16 Gram + wave top-32 filter -------------
// Block 256 thr (4 waves). Rows: 64 per block (fixed). Cols: 64 per m-step.
// Wave w computes one 32x32 tile: rh=w&1 (row half), ch=w>>1 (col half).
// A-frags (hi+lo, K=64) PRELOADED TO REGISTERS once. B staged to LDS per step.
// acc = A_hi*B_hi + A_hi*B_lo + A_lo*B_hi (3 MFMAs per K=16 chunk, 12/step).
// Ranking key s = acc - 0.5*xx_m written to Ds[col][row] (dbuf), selection =
// proven ballot-insert distributed top-64, emit lanes 0..31 (top-32 approx).
// LDS: Bs 64x72 ushort x2 planes = 18432 B | Ds dbuf 2 x 64x66 f32 = 33792 B
// total 52224 B -> 3 blocks/CU.
__launch_bounds__(256, 3)
__global__ void k_knn(const ushort* __restrict__ xth, const ushort* __restrict__ xtl,
                      const float* __restrict__ xx, int* __restrict__ ci) {
  __shared__ __align__(16) char SMEM[52224];
  ushort* Bh = (ushort*)SMEM;                 // [p*72 + c]
  ushort* Bl = Bh + 64 * 72;
  float* Dd = (float*)(SMEM + 18432);         // 2 x [col*66 + row]
  int tid = threadIdx.x;
  int lane = tid & 63, w = tid >> 6;
  int rh = w & 1, ch = w >> 1;
  int nb = blockIdx.x, b = blockIdx.y;
  int n0 = nb * 64;
  const ushort* xh = xth + (size_t)b * NPTS * 64;
  const ushort* xl = xtl + (size_t)b * NPTS * 64;
  const float* xxb = xx + b * NPTS;

#define STAGE(dh, dl, p0)                                                \
  {                                                                      \
    _Pragma("unroll")                                                    \
    for (int k = 0; k < 2; ++k) {                                        \
      int q = tid + 256 * k;                                             \
      int p = q >> 3, c8 = (q & 7) << 3;                                 \
      int4 vh = *(const int4*)(xh + (size_t)((p0) + p) * 64 + c8);       \
      int4 vl = *(const int4*)(xl + (size_t)((p0) + p) * 64 + c8);       \
      *(int4*)((dh) + p * 72 + c8) = vh;                                 \
      *(int4*)((dl) + p * 72 + c8) = vl;                                 \
    }                                                                    \
  }

  // ---- stage A-tile (rows n0..n0+63) into Dd region, load frags to regs ----
  ushort* Ah_lds = (ushort*)Dd;
  ushort* Al_lds = Ah_lds + 64 * 72;
  STAGE(Ah_lds, Al_lds, n0)
  __syncthreads();
  s8v Ah[4], Al[4];
  {
    int arow = 32 * rh + (lane & 31);
    int aofs = arow * 72 + 8 * (lane >> 5);
#pragma unroll
    for (int kc = 0; kc < 4; ++kc) {
      Ah[kc] = *(const s8v*)(Ah_lds + aofs + 16 * kc);
      Al[kc] = *(const s8v*)(Al_lds + aofs + 16 * kc);
    }
  }
  // stage B(0) (different LDS region; A-frag reads already done per-thread)
  STAGE(Bh, Bl, 0)

  // distributed top list (64-deep, emit 32): lane l = l-th best of row 16w+r
  float val[16]; int idx[16];
#pragma unroll
  for (int r = 0; r < 16; ++r) { val[r] = NEG_INF; idx[r] = 0; }

  int fcol = 32 * ch + (lane & 31);
  int fofs = fcol * 72 + 8 * (lane >> 5);
  int rb = 32 * rh + 4 * (lane >> 5);

  for (int mt = 0; mt < NPTS / 64; ++mt) {
    int m0 = mt * 64;
    __syncthreads();                           // Bs(mt) staged; Ds[mt&1] free
    f16v acc;
#pragma unroll
    for (int i = 0; i < 16; ++i) acc[i] = 0.f;
#pragma unroll
    for (int kc = 0; kc < 4; ++kc) {
      s8v bh = *(const s8v*)(Bh + fofs + 16 * kc);
      s8v bl = *(const s8v*)(Bl + fofs + 16 * kc);
      acc = __builtin_amdgcn_mfma_f32_32x32x16_bf16(Ah[kc], bh, acc, 0, 0, 0);
      acc = __builtin_amdgcn_mfma_f32_32x32x16_bf16(Ah[kc], bl, acc, 0, 0, 0);
      acc = __builtin_amdgcn_mfma_f32_32x32x16_bf16(Al[kc], bh, acc, 0, 0, 0);
    }
    // s-key -> Ds[col][row], C-layout: col=lane&31, row=(reg&3)+8*(reg>>2)+4*(lane>>5)
    float xm = xxb[m0 + fcol];
    float* D = Dd + (mt & 1) * (64 * 66);
    float* Dc = D + fcol * 66 + rb;
#pragma unroll
    for (int q = 0; q < 4; ++q) {
      float2 lo2, hi2;
      lo2.x = acc[4 * q + 0] - 0.5f * xm;
      lo2.y = acc[4 * q + 1] - 0.5f * xm;
      hi2.x = acc[4 * q + 2] - 0.5f * xm;
      hi2.y = acc[4 * q + 3] - 0.5f * xm;
      *(float2*)(Dc + 8 * q)     = lo2;
      *(float2*)(Dc + 8 * q + 2) = hi2;
    }
    __syncthreads();                           // frag reads done; Ds(mt) visible
    if (mt + 1 < NPTS / 64) STAGE(Bh, Bl, (mt + 1) * 64)

    // selection on Ds(mt): wave w scans rows 16w..16w+15, lane = col
    float* D2 = Dd + (mt & 1) * (64 * 66);
#pragma unroll
    for (int r = 0; r < 16; ++r) {
      int R = 16 * w + r;
      float d = D2[lane * 66 + R];
      float th = __shfl(val[r], KSEL - 1);
      unsigned long long hit = __ballot(d > th);
      while (hit) {
        int j = __builtin_ctzll(hit);
        hit &= hit - 1;
        float cv = __shfl(d, j);
        int cm = m0 + j;
        unsigned long long km = __ballot(val[r] >= cv);
        int cnt = __popcll(km);
        float sv = __shfl_up(val[r], 1);
        int si = __shfl_up(idx[r], 1);
        if (lane >= cnt) {
          val[r] = (lane == cnt) ? cv : sv;
          idx[r] = (lane == cnt) ? cm : si;
        }
      }
    }
  }

  // emit top-32 candidate indices per row
#pragma unroll
  for (int r = 0; r < 16; ++r) {
    int n = n0 + 16 * w + r;
    if (lane < KSEL) ci[(size_t)(b * NPTS + n) * KSEL + lane] = idx[r];
  }
#undef STAGE
}

// ---------------- K1b: exact fp32 refine of 32 candidates -> top-20 ---------
__global__ void k_refine(const float* __restrict__ x, const float* __restrict__ xx,
                         const int* __restrict__ ci, int* __restrict__ idxout) {
  int tid = threadIdx.x, lane = tid & 63, w = tid >> 6;
  int t = blockIdx.x * 4 + w;                  // row id
  int b = t >> 12, n = t & (NPTS - 1);
  const float* xb = x + (size_t)b * CH * NPTS;
  int m = (lane < KSEL) ? ci[(size_t)t * KSEL + lane] : 0;
  float dot = 0.f;
#pragma unroll 8
  for (int c = 0; c < CH; ++c)
    dot = fmaf(xb[(size_t)c * NPTS + n], xb[(size_t)c * NPTS + m], dot);
  float d = (2.f * dot - xx[t]) - xx[b * NPTS + m];
  // monotone key: d desc, then index asc
  unsigned u = __float_as_uint(d);
  u = (u & 0x80000000u) ? ~u : (u | 0x80000000u);
  unsigned long long key = ((unsigned long long)u << 32) | (unsigned)(NPTS - 1 - m);
  if (lane >= KSEL) key = 0ull;
  unsigned long long lk = 0ull; int mi = 0;
#pragma unroll
  for (int it = 0; it < KSEL; ++it) {
    unsigned long long ck = __shfl(key, it);
    int cm = __shfl(m, it);
    unsigned long long km = __ballot(lk > ck);
    int cnt = __popcll(km);
    unsigned long long sk = __shfl_up(lk, 1);
    int sm = __shfl_up(mi, 1);
    if (lane >= cnt) {
      lk = (lane == cnt) ? ck : sk;
      mi = (lane == cnt) ? cm : sm;
    }
  }
  if (lane < KNN) idxout[(size_t)t * KNN + lane] = mi;
}

// ---------------- K3: gather + max + leaky, transpose to (B,O,N) ------------
__global__ void k_out(const float* __restrict__ P, const float* __restrict__ Q,
                      const int* __restrict__ idx, float* __restrict__ out) {
  __shared__ float T[64 * 65];
  int tid = threadIdx.x;
  int nb = blockIdx.x, b = blockIdx.y;
  int n0 = nb * 64;
  int o = tid & 63, ng = tid >> 6;
  const float* Pb = P + (size_t)b * NPTS * 64;
  for (int p = 0; p < 16; ++p) {
    int nl = p * 4 + ng;
    int n = n0 + nl;
    const int* ip = idx + (size_t)(b * NPTS + n) * KNN;
    float mx = NEG_INF;
#pragma unroll
    for (int k = 0; k < KNN; ++k) {
      int id = ip[k];
      float v = Pb[(size_t)id * 64 + o];
      mx = fmaxf(mx, v);
    }
    float z = mx + Q[(size_t)(b * NPTS + n) * 64 + o];
    z = (z >= 0.f) ? z : NEG_SLOPE * z;
    T[o * 65 + nl] = z;
  }
  __syncthreads();
  float* ob = out + (size_t)b * 64 * NPTS + n0;
  int nl = tid & 63;
  for (int w = 0; w < 16; ++w) {
    int oo = w * 4 + ng;
    ob[(size_t)oo * NPTS + nl] = T[oo * 65 + nl];
  }
}

extern "C" void kernel_launch(void* const* d_in, const int* in_sizes, int n_in,
                              void* d_out, int out_size, void* d_ws, size_t ws_size,
                              hipStream_t stream) {
  const float* x     = (const float*)d_in[0];
  const float* W     = (const float*)d_in[1];
  const float* gamma = (const float*)d_in[2];
  const float* beta  = (const float*)d_in[3];
  const float* rmean = (const float*)d_in[4];
  const float* rvar  = (const float*)d_in[5];
  float* out = (float*)d_out;

  // ws (floats): xx 32768 | idx 655360(int) | region 4194304:
  //   phase A: xt_hi 1048576 | xt_lo 1048576 | ci 1048576   (cvt->knn->refine)
  //   phase B: P 2097152 | Q 2097152                         (pq->out, overlaps A)
  float* xx  = (float*)d_ws;
  int*   idx = (int*)(xx + 32768);
  float* reg = (float*)(idx + 655360);
  ushort* xth = (ushort*)reg;
  ushort* xtl = (ushort*)(reg + 1048576);
  int*    ci  = (int*)(reg + 2097152);
  float* P   = reg;
  float* Q   = reg + 2097152;

  k_xx<<<BATCH * NPTS / 256, 256, 0, stream>>>(x, xx);
  k_cvt<<<dim3(NPTS / 64, BATCH), 256, 0, stream>>>(x, xth, xtl);
  k_knn<<<dim3(NPTS / 64, BATCH), 256, 0, stream>>>(xth, xtl, xx, ci);
  k_refine<<<BATCH * NPTS / 4, 256, 0, stream>>>(x, xx, ci, idx);
  k_pq<<<BATCH * NPTS / 16, 256, 0, stream>>>(x, W, gamma, beta, rmean, rvar, P, Q);
  k_out<<<dim3(NPTS / 64, BATCH), 256, 0, stream>>>(P, Q, idx, out);
}